// Round 5
// baseline (250.403 us; speedup 1.0000x reference)
//
#include <hip/hip_runtime.h>
#include <cmath>

#define DIM 384
#define IMG 112
#define IMG2 (IMG*IMG)          // 12544
#define FINALN 16
#define PATCH 49
#define SPS 50                  // padded patch stride (bf16 elems) -> dword-aligned rows
#define DROP_P 0.2f

// fp32 -> bf16, round-to-nearest-even (data is finite; no NaN path needed)
__device__ __forceinline__ unsigned short f2bf_rne(float x) {
    unsigned int u = __float_as_uint(x);
    u += 0x7fffu + ((u >> 16) & 1u);
    return (unsigned short)(u >> 16);
}
__device__ __forceinline__ float bf2f(unsigned short s) {
    return __uint_as_float(((unsigned int)s) << 16);
}

// Fully fused: one block per output patch (b,h,w). 2048 blocks x 512 threads.
// LDS: sp bf16 384x50 = 37.5 KB + aw 1.5 KB + partials 1.5 KB = 40.5 KB
//   -> 3 blocks/CU (24 waves/CU, vs 16 at fp32 sp). hr read EXACTLY once.
__global__ __launch_bounds__(512, 6) void kFused(const float* __restrict__ hr,
                                                 const float* __restrict__ du,
                                                 const float* __restrict__ aw,
                                                 const float* __restrict__ ab,
                                                 const float* __restrict__ wmat,
                                                 const float* __restrict__ bmat,
                                                 float* __restrict__ out) {
    __shared__ unsigned int sp_u[DIM * SPS / 2];   // 38400 B, dword-aligned
    __shared__ float s_aw[DIM];
    __shared__ float s_red[8 * PATCH];             // 392 logit partials, then 49 attn
    unsigned short* sp = (unsigned short*)sp_u;

    int tid = threadIdx.x;

    // XCD-locality swizzle: each XCD gets one batch image's 256 patches, so
    // w-adjacent patches (sharing 64B hr sectors) hit the same per-XCD L2.
    int id  = blockIdx.x;                 // 0..2047
    int nid = (id & 7) * 256 + (id >> 3);
    int b = nid >> 8;
    int h = (nid >> 4) & 15;
    int w = nid & 15;

    // ---- prefetch tiny scalars off the critical path (wave 0 uses them later) ----
    float duv = 0.f, abv = 0.f, wv = 0.f, bv = 0.f;
    if (tid < 64) {
        if (tid < PATCH) { wv = wmat[tid]; bv = bmat[tid]; }
        duv = du[(b << 8) + (h << 4) + w];
        abv = ab[0];
    }
    if (tid < DIM) s_aw[tid] = aw[tid];

    // ---- stage patch: 2688 runs (c,i) of 7 contiguous floats, quantize to bf16 ----
    const float* base = hr + (size_t)b * DIM * IMG2 + (size_t)(7 * h) * IMG + 7 * w;
    #pragma unroll
    for (int k = 0; k < 6; ++k) {
        int r = tid + k * 512;
        if (r < DIM * 7) {
            int c = r / 7;
            int i = r - c * 7;
            const float* p = base + (size_t)c * IMG2 + i * IMG;
            float v[7];
            #pragma unroll
            for (int j = 0; j < 7; ++j) v[j] = p[j];
            unsigned short* d = sp + c * SPS + i * 7;
            #pragma unroll
            for (int j = 0; j < 7; ++j) d[j] = f2bf_rne(v[j]);
        }
    }
    __syncthreads();

    // ---- logits: 8 groups x 48 channels, threads 0..391 ----
    if (tid < 8 * PATCH) {
        int g = tid / PATCH;            // 0..7
        int p = tid - g * PATCH;        // 0..48
        int c0 = g * 48;
        float acc = 0.f;
        #pragma unroll 8
        for (int c = 0; c < 48; ++c)
            acc = fmaf(bf2f(sp[(c0 + c) * SPS + p]), s_aw[c0 + c], acc);
        s_red[tid] = acc;
    }
    __syncthreads();

    // ---- wave 0: finalize logits, masked affine, softmax over 49 ----
    if (tid < 64) {
        float al = -1e30f;
        if (tid < PATCH) {
            float logit = abv;
            #pragma unroll
            for (int g = 0; g < 8; ++g) logit += s_red[g * PATCH + tid];
            float mask = (duv > DROP_P) ? 1.0f : 0.0f;
            al = fmaf(logit * mask, wv, bv);
        }
        float m = al;
        #pragma unroll
        for (int d = 32; d >= 1; d >>= 1) m = fmaxf(m, __shfl_xor(m, d, 64));
        float e = (tid < PATCH) ? __expf(al - m) : 0.f;
        float s = e;
        #pragma unroll
        for (int d = 32; d >= 1; d >>= 1) s += __shfl_xor(s, d, 64);
        if (tid < PATCH) s_red[tid] = e / s;   // attn
    }
    __syncthreads();

    // ---- output: thread -> channel; packed dword reads (2 bf16 each).
    //      lane stride = 25 dwords -> only 2-way bank aliasing (free). ----
    if (tid < DIM) {
        const unsigned int* pu = sp_u + tid * (SPS / 2);
        float acc = 0.f;
        #pragma unroll
        for (int k = 0; k < 24; ++k) {
            unsigned int u = pu[k];
            float lo = __uint_as_float(u << 16);
            float hi = __uint_as_float(u & 0xffff0000u);
            acc = fmaf(lo, s_red[2 * k], acc);
            acc = fmaf(hi, s_red[2 * k + 1], acc);
        }
        acc = fmaf(__uint_as_float(pu[24] << 16), s_red[48], acc);
        out[(((size_t)b * DIM + tid) * FINALN + h) * FINALN + w] = acc;
    }
}

extern "C" void kernel_launch(void* const* d_in, const int* in_sizes, int n_in,
                              void* d_out, int out_size, void* d_ws, size_t ws_size,
                              hipStream_t stream) {
    const float* hr   = (const float*)d_in[0];
    // d_in[1] = guidance (unused by reference)
    const float* du   = (const float*)d_in[2];
    const float* aw   = (const float*)d_in[3];
    const float* ab   = (const float*)d_in[4];
    const float* wmat = (const float*)d_in[5];
    const float* bmat = (const float*)d_in[6];
    float* out = (float*)d_out;

    kFused<<<2048, 512, 0, stream>>>(hr, du, aw, ab, wmat, bmat, out);
}

// Round 6
// 248.716 us; speedup vs baseline: 1.0068x; 1.0068x over previous
//
#include <hip/hip_runtime.h>
#include <cmath>

#define DIM 384
#define IMG 112
#define IMG2 (IMG*IMG)          // 12544
#define FINALN 16
#define PATCH 49
#define DROP_P 0.2f

// Fully fused: one block per output patch (b,h,w). 2048 blocks x 512 threads.
// LDS: patch (384*49 fp32 = 75.3 KB) + aw (1.5 KB) + partials (1.5 KB) = 78.3 KB
//   -> 2 blocks/CU, 16 waves/CU. hr read EXACTLY once (and L3-hot from the
//   harness restore copy). Floor = 154 MB read + 3 MB write.
// R5 post-mortem: bf16 LDS (3 blocks/CU) regressed — phase-latency-bound, not
// wave-starved; keep fp32 staging with zero repack VALU on the load path.
__global__ __launch_bounds__(512) void kFused(const float* __restrict__ hr,
                                              const float* __restrict__ du,
                                              const float* __restrict__ aw,
                                              const float* __restrict__ ab,
                                              const float* __restrict__ wmat,
                                              const float* __restrict__ bmat,
                                              float* __restrict__ out) {
    __shared__ float sp[DIM * PATCH];   // patch, c-major: sp[c*49 + i*7 + j]
    __shared__ float s_aw[DIM];
    __shared__ float s_red[8 * PATCH];  // 392 logit partials, then 49 attn

    int tid = threadIdx.x;

    // XCD-locality swizzle: each XCD gets a contiguous stripe of patch ids so
    // w-adjacent patches (sharing 64B hr sectors) hit the same per-XCD L2.
    int id  = blockIdx.x;                 // 0..2047
    int nid = (id & 7) * 256 + (id >> 3);
    int b = nid >> 8;
    int h = (nid >> 4) & 15;
    int w = nid & 15;

    // ---- prefetch tiny scalars off the critical path (used by wave 0 later) ----
    float duv = 0.f, abv = 0.f, wv = 0.f, bv = 0.f;
    if (tid < 64) {
        if (tid < PATCH) { wv = wmat[tid]; bv = bmat[tid]; }
        duv = du[(b << 8) + (h << 4) + w];
        abv = ab[0];
    }
    for (int i = tid; i < DIM; i += 512) s_aw[i] = aw[i];

    // ---- stage patch: 2688 runs (c,i) of 7 contiguous floats ----
    const float* base = hr + (size_t)b * DIM * IMG2 + (size_t)(7 * h) * IMG + 7 * w;
    #pragma unroll
    for (int k = 0; k < 6; ++k) {
        int r = tid + k * 512;
        if (r < DIM * 7) {
            int c = r / 7;
            int i = r - c * 7;
            const float* p = base + (size_t)c * IMG2 + i * IMG;
            float* d = sp + c * PATCH + i * 7;
            #pragma unroll
            for (int j = 0; j < 7; ++j) d[j] = p[j];
        }
    }
    __syncthreads();

    // ---- logits: 8 groups x 48 channels, threads 0..391 ----
    if (tid < 8 * PATCH) {
        int g = tid / PATCH;            // 0..7
        int p = tid - g * PATCH;        // 0..48
        int c0 = g * 48;
        float acc = 0.f;
        #pragma unroll 8
        for (int c = 0; c < 48; ++c)
            acc = fmaf(sp[(c0 + c) * PATCH + p], s_aw[c0 + c], acc);
        s_red[tid] = acc;
    }
    __syncthreads();

    // ---- wave 0: finalize logits, masked affine, softmax over 49 ----
    if (tid < 64) {
        float al = -1e30f;
        if (tid < PATCH) {
            float logit = abv;
            #pragma unroll
            for (int g = 0; g < 8; ++g) logit += s_red[g * PATCH + tid];
            float mask = (duv > DROP_P) ? 1.0f : 0.0f;
            al = fmaf(logit * mask, wv, bv);
        }
        float m = al;
        #pragma unroll
        for (int d = 32; d >= 1; d >>= 1) m = fmaxf(m, __shfl_xor(m, d, 64));
        float e = (tid < PATCH) ? __expf(al - m) : 0.f;
        float s = e;
        #pragma unroll
        for (int d = 32; d >= 1; d >>= 1) s += __shfl_xor(s, d, 64);
        if (tid < PATCH) s_red[tid] = e / s;   // attn
    }
    __syncthreads();

    // ---- output: thread -> channel; sp stride-49 across lanes (odd stride =
    //      full bank permutation, conflict-free); s_red[p] broadcast ----
    if (tid < DIM) {
        const float* pc = sp + tid * PATCH;
        float acc = 0.f;
        #pragma unroll
        for (int p = 0; p < PATCH; ++p)
            acc = fmaf(pc[p], s_red[p], acc);
        out[(((size_t)b * DIM + tid) * FINALN + h) * FINALN + w] = acc;
    }
}

extern "C" void kernel_launch(void* const* d_in, const int* in_sizes, int n_in,
                              void* d_out, int out_size, void* d_ws, size_t ws_size,
                              hipStream_t stream) {
    const float* hr   = (const float*)d_in[0];
    // d_in[1] = guidance (unused by reference)
    const float* du   = (const float*)d_in[2];
    const float* aw   = (const float*)d_in[3];
    const float* ab   = (const float*)d_in[4];
    const float* wmat = (const float*)d_in[5];
    const float* bmat = (const float*)d_in[6];
    float* out = (float*)d_out;

    kFused<<<2048, 512, 0, stream>>>(hr, du, aw, ab, wmat, bmat, out);
}